// Round 11
// baseline (79.868 us; speedup 1.0000x reference)
//
#include <hip/hip_runtime.h>
#include <hip/hip_cooperative_groups.h>
#include <hip/hip_bf16.h>
#include <math.h>

// R10: ONE cooperative kernel (single graph node).
// S[target r][pred c] = 0.5*t^2 - p.t via v_mfma_f32_32x32x16_bf16 with the
// R7-validated hi/lo bf16 K-packing (absmax ~0):
//   A row r (target): k0-2=th, k3-5=th, k6-8=tl | k9=qh, k10=ql
//   B col c (pred)  : k0-2=-ph, k3-5=-pl, k6-8=-ph | k9=1, k10=1
// d^2/2 = dot + 0.5*p^2 (pred-only, added in epilogue after the min).
// Grid 512 = (batch, 64-pred panel), 2 blocks/CU co-resident (64KB LDS each).
// Waves: pred tile = w>>1, target half = w&1 -> 32 MFMA per wave; halves
// merged in LDS, epilogue + panel partial in-block; grid.sync(); block 0
// sums 512 partials in fixed order -> out[0]. No memset, no atomics.

typedef short short8 __attribute__((ext_vector_type(8)));
typedef float f32x16 __attribute__((ext_vector_type(16)));

__device__ __forceinline__ unsigned short f2bf(float f) {  // RNE f32->bf16
  unsigned u = __float_as_uint(f);
  u = u + 0x7FFFu + ((u >> 16) & 1u);
  return (unsigned short)(u >> 16);
}
__device__ __forceinline__ float bf2f(unsigned short h) {
  return __uint_as_float(((unsigned)h) << 16);
}

#define TPB 256
#define NPTS 2048

__global__ __launch_bounds__(TPB, 2) void chamfer_coop_kernel(
    const float* __restrict__ pred, const float* __restrict__ targ,
    const float* __restrict__ sym_flag, float* __restrict__ partial,
    float* __restrict__ out, int N, int B, int panelsPerBatch, float invNB) {
  __shared__ short8 sA[2][NPTS];  // 64 KB packed A fragments (both K-halves)
  __shared__ float sm[4][32];     // per-wave col mins
  __shared__ float sW[4];

  const int blk = blockIdx.x;
  const int pp = blk % panelsPerBatch;  // 64-pred panel (32 per batch)
  const int b = blk / panelsPerBatch;

  // ---- stage + convert ALL targets of this batch (8 per thread)
  const float* tb = targ + (size_t)b * N * 3;
  for (int t = threadIdx.x; t < N; t += TPB) {
    const float x = tb[t * 3], y = tb[t * 3 + 1], z = tb[t * 3 + 2];
    const unsigned short thx = f2bf(x), thy = f2bf(y), thz = f2bf(z);
    const unsigned short tlx = f2bf(x - bf2f(thx));
    const unsigned short tly = f2bf(y - bf2f(thy));
    const unsigned short tlz = f2bf(z - bf2f(thz));
    const float q = 0.5f * (x * x + y * y + z * z);
    const unsigned short qh = f2bf(q), ql = f2bf(q - bf2f(qh));
    sA[0][t] = short8{(short)thx, (short)thy, (short)thz, (short)thx,
                      (short)thy, (short)thz, (short)tlx, (short)tly};
    sA[1][t] = short8{(short)tlz, (short)qh, (short)ql, 0, 0, 0, 0, 0};
  }

  const int lane = threadIdx.x & 63;
  const int w = threadIdx.x >> 6;
  const int g = lane >> 5;    // K-half this lane supplies
  const int l31 = lane & 31;
  const int tile = w >> 1;    // 0..1: which 32-pred tile
  const int half = w & 1;     // 0..1: which 1024-target half
  const int col = pp * 64 + tile * 32 + l31;  // this lane's pred column

  // ---- B fragment (negated hi/lo split) for this lane's pred col
  const float* pq = pred + ((size_t)b * N + col) * 3;
  const float px = pq[0], py = pq[1], pz = pq[2];
  short8 bfr;
  {
    const unsigned short hx = f2bf(-px), hy = f2bf(-py), hz = f2bf(-pz);
    const unsigned short lx = f2bf(-px - bf2f(hx));
    const unsigned short ly = f2bf(-py - bf2f(hy));
    const unsigned short lz = f2bf(-pz - bf2f(hz));
    if (g == 0)
      bfr = short8{(short)hx, (short)hy, (short)hz, (short)lx,
                   (short)ly, (short)lz, (short)hx, (short)hy};
    else
      bfr = short8{(short)hz, (short)0x3F80, (short)0x3F80, 0, 0, 0, 0, 0};
  }
  __syncthreads();

  const f32x16 zc = {0.f, 0.f, 0.f, 0.f, 0.f, 0.f, 0.f, 0.f,
                     0.f, 0.f, 0.f, 0.f, 0.f, 0.f, 0.f, 0.f};
  float rm[8];
#pragma unroll
  for (int i = 0; i < 8; ++i) rm[i] = 3.4e38f;

  // ---- 32 MFMA over this wave's 1024-target half
  const int tbase = half * (NPTS / 2 / 32);  // starting 32-target tile
#pragma unroll 4
  for (int ta = 0; ta < NPTS / 2 / 32; ++ta) {
    const short8 a = sA[g][(tbase + ta) * 32 + l31];
    const f32x16 d = __builtin_amdgcn_mfma_f32_32x32x16_bf16(a, bfr, zc, 0, 0, 0);
#pragma unroll
    for (int i = 0; i < 8; ++i)
      rm[i] = fminf(rm[i], fminf(d[2 * i], d[2 * i + 1]));  // v_min3
  }

  // ---- per-col min for this half: in-lane tree + cross-row-half merge
  float m = rm[0];
#pragma unroll
  for (int i = 1; i < 8; ++i) m = fminf(m, rm[i]);
  m = fminf(m, __shfl_xor(m, 32));
  if (lane < 32) sm[w][l31] = m;
  __syncthreads();

  // ---- epilogue: threads 0..63 own the panel's 64 preds
  float c = 0.f;
  if (threadIdx.x < 64) {
    const int i = threadIdx.x;
    const int ct = i >> 5, cl = i & 31;
    const float mm = fminf(sm[ct * 2 + 0][cl], sm[ct * 2 + 1][cl]);
    const size_t gc = (size_t)b * N + pp * 64 + i;
    const float x = pred[gc * 3], y = pred[gc * 3 + 1], z = pred[gc * 3 + 2];
    const float tx = targ[gc * 3], ty = targ[gc * 3 + 1], tz = targ[gc * 3 + 2];
    const float hp2 = 0.5f * (x * x + y * y + z * z);
    const float dsym = sqrtf(fmaxf(2.f * (mm + hp2), 1e-12f));
    const float dx = x - tx, dy = y - ty, dz = z - tz;
    const float dasym = sqrtf(dx * dx + dy * dy + dz * dz);
    const float f = sym_flag[b];
    c = f * dsym + (1.f - f) * dasym;
#pragma unroll
    for (int off = 32; off > 0; off >>= 1) c += __shfl_xor(c, off);
    if (i == 0) partial[blk] = c;  // plain store, deterministic
  }

  // ---- single grid barrier, then block 0 reduces 512 partials
  __threadfence();
  cooperative_groups::this_grid().sync();

  if (blk == 0) {
    const int t = threadIdx.x;
    float s = __hip_atomic_load(&partial[t], __ATOMIC_RELAXED,
                                __HIP_MEMORY_SCOPE_AGENT) +
              __hip_atomic_load(&partial[t + 256], __ATOMIC_RELAXED,
                                __HIP_MEMORY_SCOPE_AGENT);
#pragma unroll
    for (int off = 32; off > 0; off >>= 1) s += __shfl_xor(s, off);
    if ((t & 63) == 0) sW[t >> 6] = s;
    __syncthreads();
    if (t == 0) out[0] = (sW[0] + sW[1] + sW[2] + sW[3]) * invNB;
  }
}

extern "C" void kernel_launch(void* const* d_in, const int* in_sizes, int n_in,
                              void* d_out, int out_size, void* d_ws, size_t ws_size,
                              hipStream_t stream) {
  const float* pred = (const float*)d_in[0];
  const float* targ = (const float*)d_in[1];
  const float* sym_flag = (const float*)d_in[2];
  float* out = (float*)d_out;

  int B = in_sizes[2];            // 16
  int N = in_sizes[0] / (B * 3);  // 2048 (kernel sized for this)

  int panelsPerBatch = N / 64;    // 32
  int grid = B * panelsPerBatch;  // 512 blocks = 2 per CU
  float* partial = (float*)d_ws;  // grid floats
  float invNB = 1.0f / (float)(N * B);

  void* args[] = {&pred, &targ, &sym_flag, &partial, &out,
                  &N, &B, &panelsPerBatch, &invNB};
  hipLaunchCooperativeKernel((const void*)chamfer_coop_kernel, dim3(grid),
                             dim3(TPB), args, 0, stream);
}

// Round 12
// 14.859 us; speedup vs baseline: 5.3752x; 5.3752x over previous
//
#include <hip/hip_runtime.h>
#include <hip/hip_bf16.h>
#include <math.h>

// R11: 2 minimal nodes.
// k1: block = (batch, 64-pred panel), grid 512 (2 blocks/CU, 64KB LDS).
//     All 2048 targets packed in LDS once per block; the 4 waves each own a
//     512-target QUARTER and both 32-pred tiles (2 independent MFMAs/iter).
//     Full min over all targets completes IN-BLOCK (LDS quarter-merge), then
//     epilogue (d^2/2 -> dist, asym, blend) and ONE f32 partial per block.
// k2: one block sums 512 partials in fixed order -> out[0].
// MFMA packing (R7/R8/R10-validated, absmax ~0):
//   A row r (target): k0-2=th, k3-5=th, k6-8=tl | k9=qh, k10=ql
//   B col c (pred)  : k0-2=-ph, k3-5=-pl, k6-8=-ph | k9=1, k10=1
//   dot = 0.5*t^2 - p.t;  d^2/2 = dot + 0.5*p^2 (added in epilogue).

typedef short short8 __attribute__((ext_vector_type(8)));
typedef float f32x16 __attribute__((ext_vector_type(16)));

__device__ __forceinline__ unsigned short f2bf(float f) {  // RNE f32->bf16
  unsigned u = __float_as_uint(f);
  u = u + 0x7FFFu + ((u >> 16) & 1u);
  return (unsigned short)(u >> 16);
}
__device__ __forceinline__ float bf2f(unsigned short h) {
  return __uint_as_float(((unsigned)h) << 16);
}

#define TPB 256
#define NPTS 2048

__global__ __launch_bounds__(TPB, 2) void chamfer_main_kernel(
    const float* __restrict__ pred, const float* __restrict__ targ,
    const float* __restrict__ sym_flag, float* __restrict__ partial,
    int N, int B, int panelsPerBatch) {
  __shared__ short8 sA[2][NPTS];  // 64 KB packed A fragments (both K-halves)
  __shared__ float sm[4][64];     // per-quarter col mins

  const int blk = blockIdx.x;
  const int pp = blk % panelsPerBatch;  // 64-pred panel (32 per batch)
  const int b = blk / panelsPerBatch;

  // ---- stage + pack ALL targets of this batch (8 per thread)
  const float* tb = targ + (size_t)b * N * 3;
  for (int t = threadIdx.x; t < NPTS; t += TPB) {
    const float x = tb[t * 3], y = tb[t * 3 + 1], z = tb[t * 3 + 2];
    const unsigned short thx = f2bf(x), thy = f2bf(y), thz = f2bf(z);
    const unsigned short tlx = f2bf(x - bf2f(thx));
    const unsigned short tly = f2bf(y - bf2f(thy));
    const unsigned short tlz = f2bf(z - bf2f(thz));
    const float q = 0.5f * (x * x + y * y + z * z);
    const unsigned short qh = f2bf(q), ql = f2bf(q - bf2f(qh));
    sA[0][t] = short8{(short)thx, (short)thy, (short)thz, (short)thx,
                      (short)thy, (short)thz, (short)tlx, (short)tly};
    sA[1][t] = short8{(short)tlz, (short)qh, (short)ql, 0, 0, 0, 0, 0};
  }

  const int lane = threadIdx.x & 63;
  const int w = threadIdx.x >> 6;  // wave = target quarter 0..3
  const int g = lane >> 5;         // K-half this lane supplies
  const int l31 = lane & 31;
  const int colBase = pp * 64;

  // ---- B fragments for BOTH 32-pred tiles of the panel (negated hi/lo)
  short8 bf0, bf1;
#pragma unroll
  for (int pt = 0; pt < 2; ++pt) {
    const int col = colBase + pt * 32 + l31;
    const float* pq = pred + ((size_t)b * N + col) * 3;
    const float x = pq[0], y = pq[1], z = pq[2];
    const unsigned short hx = f2bf(-x), hy = f2bf(-y), hz = f2bf(-z);
    const unsigned short lx = f2bf(-x - bf2f(hx));
    const unsigned short ly = f2bf(-y - bf2f(hy));
    const unsigned short lz = f2bf(-z - bf2f(hz));
    short8 r;
    if (g == 0)
      r = short8{(short)hx, (short)hy, (short)hz, (short)lx,
                 (short)ly, (short)lz, (short)hx, (short)hy};
    else
      r = short8{(short)hz, (short)0x3F80, (short)0x3F80, 0, 0, 0, 0, 0};
    if (pt == 0) bf0 = r; else bf1 = r;
  }
  __syncthreads();

  const f32x16 zc = {0.f, 0.f, 0.f, 0.f, 0.f, 0.f, 0.f, 0.f,
                     0.f, 0.f, 0.f, 0.f, 0.f, 0.f, 0.f, 0.f};
  float rm0[8], rm1[8];
#pragma unroll
  for (int i = 0; i < 8; ++i) { rm0[i] = 3.4e38f; rm1[i] = 3.4e38f; }

  // ---- this wave's 512-target quarter: 16 x (1 ds_read + 2 indep MFMA)
#pragma unroll 4
  for (int ta = 0; ta < 16; ++ta) {
    const short8 a = sA[g][w * 512 + ta * 32 + l31];
    const f32x16 d0 = __builtin_amdgcn_mfma_f32_32x32x16_bf16(a, bf0, zc, 0, 0, 0);
    const f32x16 d1 = __builtin_amdgcn_mfma_f32_32x32x16_bf16(a, bf1, zc, 0, 0, 0);
#pragma unroll
    for (int i = 0; i < 8; ++i) {
      rm0[i] = fminf(rm0[i], fminf(d0[2 * i], d0[2 * i + 1]));  // v_min3
      rm1[i] = fminf(rm1[i], fminf(d1[2 * i], d1[2 * i + 1]));
    }
  }

  // ---- per-col min for this quarter -> LDS
  float m0 = rm0[0], m1 = rm1[0];
#pragma unroll
  for (int i = 1; i < 8; ++i) { m0 = fminf(m0, rm0[i]); m1 = fminf(m1, rm1[i]); }
  m0 = fminf(m0, __shfl_xor(m0, 32));  // merge K-half rows (lane^32)
  m1 = fminf(m1, __shfl_xor(m1, 32));
  if (lane < 32) {
    sm[w][l31] = m0;
    sm[w][32 + l31] = m1;
  }
  __syncthreads();

  // ---- epilogue: threads 0..63 own the panel's 64 preds
  if (threadIdx.x < 64) {
    const int i = threadIdx.x;
    const float mm = fminf(fminf(sm[0][i], sm[1][i]), fminf(sm[2][i], sm[3][i]));
    const size_t gc = (size_t)b * N + colBase + i;
    const float x = pred[gc * 3], y = pred[gc * 3 + 1], z = pred[gc * 3 + 2];
    const float tx = targ[gc * 3], ty = targ[gc * 3 + 1], tz = targ[gc * 3 + 2];
    const float hp2 = 0.5f * (x * x + y * y + z * z);
    const float dsym = sqrtf(fmaxf(2.f * (mm + hp2), 1e-12f));
    const float dx = x - tx, dy = y - ty, dz = z - tz;
    const float dasym = sqrtf(dx * dx + dy * dy + dz * dz);
    const float f = sym_flag[b];
    float c = f * dsym + (1.f - f) * dasym;
#pragma unroll
    for (int off = 32; off > 0; off >>= 1) c += __shfl_xor(c, off);
    if (i == 0) partial[blk] = c;  // plain store, deterministic
  }
}

// k2: one block, fixed-order sum of 512 partials.
__global__ __launch_bounds__(256) void chamfer_sum_kernel(
    const float* __restrict__ partial, float* __restrict__ out, float invNB) {
  const int t = threadIdx.x;
  float s = partial[t] + partial[t + 256];
#pragma unroll
  for (int off = 32; off > 0; off >>= 1) s += __shfl_xor(s, off);
  __shared__ float sW[4];
  if ((t & 63) == 0) sW[t >> 6] = s;
  __syncthreads();
  if (t == 0) out[0] = (sW[0] + sW[1] + sW[2] + sW[3]) * invNB;
}

extern "C" void kernel_launch(void* const* d_in, const int* in_sizes, int n_in,
                              void* d_out, int out_size, void* d_ws, size_t ws_size,
                              hipStream_t stream) {
  const float* pred = (const float*)d_in[0];
  const float* targ = (const float*)d_in[1];
  const float* sym_flag = (const float*)d_in[2];
  float* out = (float*)d_out;

  const int B = in_sizes[2];            // 16
  const int N = in_sizes[0] / (B * 3);  // 2048 (kernels sized for this)

  const int panelsPerBatch = N / 64;    // 32
  const int grid = B * panelsPerBatch;  // 512
  float* partial = (float*)d_ws;        // 512 floats

  chamfer_main_kernel<<<grid, TPB, 0, stream>>>(pred, targ, sym_flag, partial,
                                                N, B, panelsPerBatch);
  chamfer_sum_kernel<<<1, 256, 0, stream>>>(partial, out,
                                            1.0f / (float)(N * B));
}